// Round 1
// baseline (1263.622 us; speedup 1.0000x reference)
//
#include <hip/hip_runtime.h>
#include <float.h>
#include <math.h>

// NormEMAVectorQuantizer: z (8,2048,256) f32, weight (8192,256) f32 (unit rows).
// out = [ z_q (16384*256) | loss (1) | indices (16384, as float) ]
//
// Pipeline:
//  1) k_norm_z   : zn = z / max(||z||,1e-12) per row  -> ws
//  2) k_wn2      : wn2[n] = sum(w[n]^2)               -> ws
//  3) k_argmin   : per 64-row x 2048-code split, argmin_n (wn2[n] - 2*zn.w_n)
//                  (|zn|^2 is row-constant -> dropped; doesn't change argmin)
//  4) k_gather   : combine 4 splits, z_q = w[idx], loss partial sums
//  5) k_final    : loss = sum / (BT*D)

#define BT_ 16384
#define D_  256
#define N_  8192
#define BETA_ 1.0f

#define BR 64      // rows per block tile
#define BC 128     // codes per block tile
#define KB 64      // K chunk
#define SPLIT 4
#define NCP (N_ / SPLIT)   // 2048 codes per split

// ---------------- kernel 1: l2-normalize z rows ----------------
__global__ __launch_bounds__(256) void k_norm_z(const float* __restrict__ z,
                                                float* __restrict__ zn) {
  const int row  = blockIdx.x * 4 + (threadIdx.x >> 6);
  const int lane = threadIdx.x & 63;
  float4 v = *(reinterpret_cast<const float4*>(z) + (size_t)row * (D_ / 4) + lane);
  float s = v.x * v.x + v.y * v.y + v.z * v.z + v.w * v.w;
#pragma unroll
  for (int o = 32; o > 0; o >>= 1) s += __shfl_xor(s, o, 64);
  float nrm = sqrtf(s);
  float dn = fmaxf(nrm, 1e-12f);
  float4 o4 = make_float4(v.x / dn, v.y / dn, v.z / dn, v.w / dn);
  *(reinterpret_cast<float4*>(zn) + (size_t)row * (D_ / 4) + lane) = o4;
}

// ---------------- kernel 2: wn2[n] = |w_n|^2 ----------------
__global__ __launch_bounds__(256) void k_wn2(const float* __restrict__ w,
                                             float* __restrict__ wn2) {
  const int row  = blockIdx.x * 4 + (threadIdx.x >> 6);
  const int lane = threadIdx.x & 63;
  float4 v = *(reinterpret_cast<const float4*>(w) + (size_t)row * (D_ / 4) + lane);
  float s = v.x * v.x + v.y * v.y + v.z * v.z + v.w * v.w;
#pragma unroll
  for (int o = 32; o > 0; o >>= 1) s += __shfl_xor(s, o, 64);
  if (lane == 0) wn2[row] = s;
}

// ---------------- kernel 3: tiled fp32 dot + partial argmin ----------------
// grid = (BT/BR) * SPLIT = 1024 blocks, 256 threads.
// thread (tx=tid&15 -> 8 codes, ty=tid>>4 -> 4 rows), 4x8 accumulators.
// LDS float4-group XOR swizzle: c4' = c4 ^ ((row>>3)&7) -> B-reads 2-way (free).
__global__ __launch_bounds__(256) void k_argmin(const float* __restrict__ zn,
                                                const float* __restrict__ w,
                                                const float* __restrict__ wn2,
                                                float* __restrict__ part_d,
                                                int* __restrict__ part_i) {
  __shared__ float4 As4[BR * KB / 4];   // 16 KB
  __shared__ float4 Bs4[BC * KB / 4];   // 32 KB
  __shared__ float best_d[BR];
  __shared__ int   best_i[BR];

  const int tid = threadIdx.x;
  const int tx = tid & 15;
  const int ty = tid >> 4;
  const int s   = blockIdx.x & (SPLIT - 1);
  const int rt  = blockIdx.x >> 2;
  const int row0 = rt * BR;
  const int n0   = s * NCP;

  const float4* znG = reinterpret_cast<const float4*>(zn);
  const float4* wG  = reinterpret_cast<const float4*>(w);

  if (tid < BR) { best_d[tid] = FLT_MAX; best_i[tid] = 0; }
  __syncthreads();

  for (int ct = 0; ct < NCP / BC; ++ct) {   // 16 code tiles
    const int c0 = n0 + ct * BC;
    float acc[4][8];
#pragma unroll
    for (int i = 0; i < 4; ++i)
#pragma unroll
      for (int j = 0; j < 8; ++j) acc[i][j] = 0.0f;

    for (int k0 = 0; k0 < D_; k0 += KB) {
      __syncthreads();   // protect As/Bs from previous readers
      // stage A: 64 rows x 16 float4-groups = 1024 groups
#pragma unroll
      for (int q = 0; q < 4; ++q) {
        int g = q * 256 + tid;
        int r = g >> 4, c4 = g & 15;
        float4 v = znG[(size_t)(row0 + r) * (D_ / 4) + (k0 >> 2) + c4];
        As4[r * 16 + (c4 ^ ((r >> 3) & 7))] = v;
      }
      // stage B: 128 rows x 16 groups = 2048 groups
#pragma unroll
      for (int q = 0; q < 8; ++q) {
        int g = q * 256 + tid;
        int r = g >> 4, c4 = g & 15;
        float4 v = wG[(size_t)(c0 + r) * (D_ / 4) + (k0 >> 2) + c4];
        Bs4[r * 16 + (c4 ^ ((r >> 3) & 7))] = v;
      }
      __syncthreads();

      for (int kk4 = 0; kk4 < KB / 4; ++kk4) {
        float4 a[4], b[8];
#pragma unroll
        for (int i = 0; i < 4; ++i) {
          int r = ty * 4 + i;
          a[i] = As4[r * 16 + (kk4 ^ ((r >> 3) & 7))];
        }
#pragma unroll
        for (int j = 0; j < 8; ++j) {
          int c = tx * 8 + j;
          b[j] = Bs4[c * 16 + (kk4 ^ ((c >> 3) & 7))];
        }
#pragma unroll
        for (int i = 0; i < 4; ++i)
#pragma unroll
          for (int j = 0; j < 8; ++j) {
            acc[i][j] = fmaf(a[i].x, b[j].x, acc[i][j]);
            acc[i][j] = fmaf(a[i].y, b[j].y, acc[i][j]);
            acc[i][j] = fmaf(a[i].z, b[j].z, acc[i][j]);
            acc[i][j] = fmaf(a[i].w, b[j].w, acc[i][j]);
          }
      }
    }
    __syncthreads();   // done reading As/Bs; reuse as candidate scratch

    // per-thread candidate (min over its 8 codes), codes ascending for first-min
    float cd[4]; int ci[4];
#pragma unroll
    for (int i = 0; i < 4; ++i) { cd[i] = FLT_MAX; ci[i] = 0; }
#pragma unroll
    for (int j = 0; j < 8; ++j) {
      int c = c0 + tx * 8 + j;
      float wnc = wn2[c];
#pragma unroll
      for (int i = 0; i < 4; ++i) {
        float dd = fmaf(-2.0f, acc[i][j], wnc);
        if (dd < cd[i]) { cd[i] = dd; ci[i] = c; }
      }
    }
    float* cd_s = reinterpret_cast<float*>(As4);   // [BR][16]
    int*   ci_s = reinterpret_cast<int*>(Bs4);     // [BR][16]
#pragma unroll
    for (int i = 0; i < 4; ++i) {
      int r = ty * 4 + i;
      cd_s[r * 16 + tx] = cd[i];
      ci_s[r * 16 + tx] = ci[i];
    }
    __syncthreads();
    if (tid < BR) {
      float bd = best_d[tid]; int bi = best_i[tid];
#pragma unroll
      for (int t = 0; t < 16; ++t) {          // tx ascending = codes ascending
        float dd = cd_s[tid * 16 + t];
        int   cc = ci_s[tid * 16 + t];
        if (dd < bd) { bd = dd; bi = cc; }
      }
      best_d[tid] = bd; best_i[tid] = bi;
    }
    __syncthreads();
  }

  if (tid < BR) {
    part_d[s * BT_ + row0 + tid] = best_d[tid];
    part_i[s * BT_ + row0 + tid] = best_i[tid];
  }
}

// ---------------- kernel 4: combine splits, gather, loss ----------------
__global__ __launch_bounds__(256) void k_gather(const float* __restrict__ zn,
                                                const float* __restrict__ w,
                                                const float* __restrict__ part_d,
                                                const int* __restrict__ part_i,
                                                float* __restrict__ zq,
                                                float* __restrict__ idx_out,
                                                float* __restrict__ loss_acc) {
  const int row  = blockIdx.x * 4 + (threadIdx.x >> 6);
  const int lane = threadIdx.x & 63;
  float bd = FLT_MAX; int bi = 0;
#pragma unroll
  for (int ss = 0; ss < SPLIT; ++ss) {   // split ascending = codes ascending
    float dd = part_d[ss * BT_ + row];
    int   cc = part_i[ss * BT_ + row];
    if (dd < bd) { bd = dd; bi = cc; }
  }
  float4 cv = *(reinterpret_cast<const float4*>(w)  + (size_t)bi  * (D_ / 4) + lane);
  float4 zv = *(reinterpret_cast<const float4*>(zn) + (size_t)row * (D_ / 4) + lane);
  *(reinterpret_cast<float4*>(zq) + (size_t)row * (D_ / 4) + lane) = cv;
  float dx = cv.x - zv.x, dy = cv.y - zv.y, dz = cv.z - zv.z, dw = cv.w - zv.w;
  float s = dx * dx + dy * dy + dz * dz + dw * dw;
#pragma unroll
  for (int o = 32; o > 0; o >>= 1) s += __shfl_xor(s, o, 64);
  if (lane == 0) {
    atomicAdd(loss_acc, s);
    idx_out[row] = (float)bi;
  }
}

// ---------------- kernel 5: finalize loss ----------------
__global__ void k_final(const float* __restrict__ loss_acc,
                        float* __restrict__ loss_out) {
  *loss_out = BETA_ * (*loss_acc) * (1.0f / (float)(BT_ * D_));
}

extern "C" void kernel_launch(void* const* d_in, const int* in_sizes, int n_in,
                              void* d_out, int out_size, void* d_ws, size_t ws_size,
                              hipStream_t stream) {
  const float* z = (const float*)d_in[0];
  const float* w = (const float*)d_in[1];

  float* out      = (float*)d_out;
  float* zq       = out;
  float* loss_out = out + (size_t)BT_ * D_;
  float* idx_out  = loss_out + 1;

  float* ws      = (float*)d_ws;
  float* zn      = ws;                               // BT*D = 16 MB
  float* wn2     = zn + (size_t)BT_ * D_;            // N
  float* part_d  = wn2 + N_;                         // SPLIT*BT
  int*   part_i  = (int*)(part_d + SPLIT * BT_);     // SPLIT*BT
  float* loss_acc = (float*)(part_i + SPLIT * BT_);  // 1

  hipMemsetAsync(loss_acc, 0, sizeof(float), stream);
  k_norm_z<<<BT_ / 4, 256, 0, stream>>>(z, zn);
  k_wn2<<<N_ / 4, 256, 0, stream>>>(w, wn2);
  k_argmin<<<(BT_ / BR) * SPLIT, 256, 0, stream>>>(zn, w, wn2, part_d, part_i);
  k_gather<<<BT_ / 4, 256, 0, stream>>>(zn, w, part_d, part_i, zq, idx_out, loss_acc);
  k_final<<<1, 1, 0, stream>>>(loss_acc, loss_out);
}

// Round 2
// 583.063 us; speedup vs baseline: 2.1672x; 2.1672x over previous
//
#include <hip/hip_runtime.h>
#include <float.h>
#include <math.h>

// NormEMAVectorQuantizer via split-bf16 MFMA + exact fp32 refinement.
// z (8,2048,256) f32, weight (8192,256) f32 (unit rows).
// out = [ z_q (16384*256) | loss (1) | indices (16384, as float) ]
//
// Pipeline:
//  1) k_prep_z  : zn = l2norm(z); split zn -> bf16 hi/lo; A_cat = [zh|zh|zl]  (K=768)
//  2) k_prep_w  : wn2 = |w|^2; split w -> bf16 hi/lo;     B_cat = [wh|wl|wh]
//  3) k_coarse  : bf16 MFMA GEMM (16384x8192x768) == zh.wh + zh.wl + zl.wh
//                 (~fp32-accurate dot, error < ~7e-5); per-row per-128-code-tile
//                 (min, secondmin, argmin) -> tm/ts/ti
//  4) k_combine : merge 64 tiles/row -> global (m,s,idx); rows with s-m <= THR
//                 flagged for exact recompute; others take coarse idx
//  5) k_refine  : flagged rows: exact fp32 distance over all tiles with
//                 tile_min <= m+THR (provably contains true argmin)
//  6) k_gather  : z_q = w[idx], loss partials, idx as float
//  7) k_final   : loss = sum / (BT*D)

#define BT_ 16384
#define D_  256
#define N_  8192
#define BETA_ 1.0f
#define THR_ 5e-4f

#define BM 128
#define BN 128
#define KSTEPS 12        // 768 / 64
#define NTILES 64        // N_ / BN

typedef __attribute__((ext_vector_type(8))) short bf16x8;
typedef __attribute__((ext_vector_type(4))) float f32x4;

__device__ __forceinline__ void gld16(void* lds, const void* g) {
  __builtin_amdgcn_global_load_lds(
      (const __attribute__((address_space(1))) void*)g,
      (__attribute__((address_space(3))) void*)lds, 16, 0, 0);
}

__device__ __forceinline__ unsigned short f2bf(float x) {
  unsigned u = __float_as_uint(x);
  u += 0x7FFFu + ((u >> 16) & 1u);
  return (unsigned short)(u >> 16);
}
__device__ __forceinline__ float bf2f(unsigned short h) {
  return __uint_as_float(((unsigned)h) << 16);
}

// ---------------- kernel 1: normalize z, store zn + split A_cat ----------------
__global__ __launch_bounds__(256) void k_prep_z(const float* __restrict__ z,
                                                float* __restrict__ zn,
                                                ushort* __restrict__ Acat) {
  const int row  = blockIdx.x * 4 + (threadIdx.x >> 6);
  const int lane = threadIdx.x & 63;
  float4 v = *(reinterpret_cast<const float4*>(z) + (size_t)row * 64 + lane);
  float s = v.x * v.x + v.y * v.y + v.z * v.z + v.w * v.w;
#pragma unroll
  for (int o = 32; o > 0; o >>= 1) s += __shfl_xor(s, o, 64);
  float dn = fmaxf(sqrtf(s), 1e-12f);
  v.x /= dn; v.y /= dn; v.z /= dn; v.w /= dn;
  *(reinterpret_cast<float4*>(zn) + (size_t)row * 64 + lane) = v;
  ushort4 h  = make_ushort4(f2bf(v.x), f2bf(v.y), f2bf(v.z), f2bf(v.w));
  ushort4 lo = make_ushort4(f2bf(v.x - bf2f(h.x)), f2bf(v.y - bf2f(h.y)),
                            f2bf(v.z - bf2f(h.z)), f2bf(v.w - bf2f(h.w)));
  ushort4* A4 = reinterpret_cast<ushort4*>(Acat);
  size_t rb = (size_t)row * 192 + lane;   // 768/4 = 192 ushort4 per row
  A4[rb]       = h;    // zh
  A4[rb + 64]  = h;    // zh
  A4[rb + 128] = lo;   // zl
}

// ---------------- kernel 2: wn2, split B_cat ----------------
__global__ __launch_bounds__(256) void k_prep_w(const float* __restrict__ w,
                                                float* __restrict__ wn2,
                                                ushort* __restrict__ Bcat) {
  const int row  = blockIdx.x * 4 + (threadIdx.x >> 6);
  const int lane = threadIdx.x & 63;
  float4 v = *(reinterpret_cast<const float4*>(w) + (size_t)row * 64 + lane);
  float s = v.x * v.x + v.y * v.y + v.z * v.z + v.w * v.w;
#pragma unroll
  for (int o = 32; o > 0; o >>= 1) s += __shfl_xor(s, o, 64);
  if (lane == 0) wn2[row] = s;
  ushort4 h  = make_ushort4(f2bf(v.x), f2bf(v.y), f2bf(v.z), f2bf(v.w));
  ushort4 lo = make_ushort4(f2bf(v.x - bf2f(h.x)), f2bf(v.y - bf2f(h.y)),
                            f2bf(v.z - bf2f(h.z)), f2bf(v.w - bf2f(h.w)));
  ushort4* B4 = reinterpret_cast<ushort4*>(Bcat);
  size_t rb = (size_t)row * 192 + lane;
  B4[rb]       = h;    // wh
  B4[rb + 64]  = lo;   // wl
  B4[rb + 128] = h;    // wh
}

// ---------------- kernel 3: bf16 MFMA GEMM + per-tile (m,s,i) ----------------
// 8192 blocks (128 row-tiles x 64 code-tiles), 256 threads (4 waves, 2x2).
__global__ __launch_bounds__(256) void k_coarse(const ushort* __restrict__ Acat,
                                                const ushort* __restrict__ Bcat,
                                                const float* __restrict__ wn2,
                                                float* __restrict__ tm,
                                                float* __restrict__ ts,
                                                int* __restrict__ ti) {
  __shared__ unsigned char As[BM * 128];   // 16 KB (128 rows x 64 bf16, swizzled)
  __shared__ unsigned char Bs[BN * 128];   // 16 KB
  __shared__ float wn2s[BN];
  __shared__ float red_m[BM][2];
  __shared__ float red_s[BM][2];
  __shared__ int   red_i[BM][2];

  const int tid = threadIdx.x;
  const int l  = tid & 63;
  const int wv = tid >> 6;
  const int wr = wv >> 1, wc = wv & 1;
  const int rt = blockIdx.x >> 6;
  const int ct = blockIdx.x & 63;
  const int row0 = rt * BM;
  const int col0 = ct * BN;

  if (tid < BN) wn2s[tid] = wn2[col0 + tid];

  // staging addresses: lds slot (r, b16) gets global (r, b16 ^ ((r&7)<<4))
  const int ra = l >> 3;                         // 0..7 row within 8-row call
  const int sb = ((l & 7) * 16) ^ (ra << 4);     // pre-swizzled source byte col
  const unsigned char* aSrc = (const unsigned char*)Acat +
      (size_t)(row0 + wv * 32 + ra) * 1536 + sb;
  const unsigned char* bSrc = (const unsigned char*)Bcat +
      (size_t)(col0 + wv * 32 + ra) * 1536 + sb;
  unsigned char* aDst = As + (wv * 32) * 128;
  unsigned char* bDst = Bs + (wv * 32) * 128;

  // fragment read offsets (swizzled)
  const int sw = (l & 7) << 4;
  const int aRowBase = (wr * 64 + (l & 15)) * 128;
  const int bRowBase = (wc * 64 + (l & 15)) * 128;
  const int off0 = (((l >> 4) * 16)) ^ sw;
  const int off1 = (((l >> 4) * 16) + 64) ^ sw;

  f32x4 acc[4][4];
#pragma unroll
  for (int i = 0; i < 4; ++i)
#pragma unroll
    for (int j = 0; j < 4; ++j) acc[i][j] = (f32x4){0.f, 0.f, 0.f, 0.f};

  for (int kb = 0; kb < KSTEPS; ++kb) {
    const size_t ko = (size_t)kb * 128;
#pragma unroll
    for (int cal = 0; cal < 4; ++cal) {
      gld16(aDst + cal * 1024, aSrc + cal * (8 * 1536) + ko);
      gld16(bDst + cal * 1024, bSrc + cal * (8 * 1536) + ko);
    }
    __syncthreads();   // drain gload_lds (compiler emits vmcnt(0) before barrier)
#pragma unroll
    for (int ks = 0; ks < 2; ++ks) {
      const int kofs = ks ? off1 : off0;
      bf16x8 af[4], bg[4];
#pragma unroll
      for (int i = 0; i < 4; ++i)
        af[i] = *(const bf16x8*)(As + aRowBase + i * 2048 + kofs);
#pragma unroll
      for (int j = 0; j < 4; ++j)
        bg[j] = *(const bf16x8*)(Bs + bRowBase + j * 2048 + kofs);
#pragma unroll
      for (int i = 0; i < 4; ++i)
#pragma unroll
        for (int j = 0; j < 4; ++j)
          acc[i][j] = __builtin_amdgcn_mfma_f32_16x16x32_bf16(af[i], bg[j], acc[i][j], 0, 0, 0);
    }
    __syncthreads();   // readers done before next stage overwrites
  }

  // epilogue: distances + per-row (m, s, idx) over this 128-code tile.
  // C layout (16x16): col = lane&15, row = (lane>>4)*4 + reg  [m89]
#pragma unroll
  for (int i = 0; i < 4; ++i) {
#pragma unroll
    for (int q = 0; q < 4; ++q) {
      float m = FLT_MAX, s = FLT_MAX; int bi = 0;
#pragma unroll
      for (int j = 0; j < 4; ++j) {
        int cl = wc * 64 + j * 16 + (l & 15);
        float d = fmaf(-2.0f, acc[i][j][q], wn2s[cl]);
        int c = col0 + cl;
        if (d < m) { s = m; m = d; bi = c; }
        else if (d < s) { s = d; }
      }
#pragma unroll
      for (int msk = 1; msk < 16; msk <<= 1) {
        float om = __shfl_xor(m, msk, 64);
        float os = __shfl_xor(s, msk, 64);
        int   oi = __shfl_xor(bi, msk, 64);
        float nsv = fminf(fminf(s, os), fmaxf(m, om));
        if (om < m || (om == m && oi < bi)) { m = om; bi = oi; }
        s = nsv;
      }
      if ((l & 15) == 0) {
        int rl = wr * 64 + i * 16 + (l >> 4) * 4 + q;
        red_m[rl][wc] = m; red_s[rl][wc] = s; red_i[rl][wc] = bi;
      }
    }
  }
  __syncthreads();
  if (tid < BM) {
    float m = red_m[tid][0], s = red_s[tid][0]; int bi = red_i[tid][0];
    float om = red_m[tid][1], os = red_s[tid][1]; int oi = red_i[tid][1];
    float nsv = fminf(fminf(s, os), fmaxf(m, om));
    if (om < m || (om == m && oi < bi)) { m = om; bi = oi; }
    s = nsv;
    size_t o = (size_t)ct * BT_ + row0 + tid;
    tm[o] = m; ts[o] = s; ti[o] = bi;
  }
}

// ---------------- kernel 4: combine tiles per row, flag ambiguous ----------------
__global__ __launch_bounds__(256) void k_combine(const float* __restrict__ tm,
                                                 const float* __restrict__ ts,
                                                 const int* __restrict__ ti,
                                                 int* __restrict__ idxf,
                                                 int* __restrict__ flagged,
                                                 int* __restrict__ count) {
  const int row = blockIdx.x * 256 + threadIdx.x;
  float m = FLT_MAX, s = FLT_MAX; int bi = 0x7fffffff;
  for (int t = 0; t < NTILES; ++t) {
    size_t o = (size_t)t * BT_ + row;
    float om = tm[o], os = ts[o]; int oi = ti[o];
    float nsv = fminf(fminf(s, os), fmaxf(m, om));
    if (om < m || (om == m && oi < bi)) { m = om; bi = oi; }
    s = nsv;
  }
  idxf[row] = bi;
  if (s - m <= THR_) {
    int p = atomicAdd(count, 1);
    flagged[p] = row;
  }
}

// ---------------- kernel 5: exact fp32 refinement of flagged rows ----------------
__global__ __launch_bounds__(256) void k_refine(const float* __restrict__ zn,
                                                const float* __restrict__ w,
                                                const float* __restrict__ wn2,
                                                const float* __restrict__ tm,
                                                const int* __restrict__ flagged,
                                                const int* __restrict__ count,
                                                int* __restrict__ idxf) {
  __shared__ float4 znr[64];
  __shared__ float tmr[64];
  __shared__ float m1s;
  __shared__ float wd[4];
  __shared__ int   wi[4];
  const int tid = threadIdx.x;
  const int cnt = *count;
  for (int f = blockIdx.x; f < cnt; f += gridDim.x) {
    __syncthreads();   // protect LDS reuse across iterations
    const int row = flagged[f];
    if (tid < 64) {
      znr[tid] = *(reinterpret_cast<const float4*>(zn) + (size_t)row * 64 + tid);
      float tv = tm[(size_t)tid * BT_ + row];
      tmr[tid] = tv;
      float mm = tv;
#pragma unroll
      for (int msk = 32; msk > 0; msk >>= 1) mm = fminf(mm, __shfl_xor(mm, msk, 64));
      if (tid == 0) m1s = mm;
    }
    __syncthreads();
    const float lim = m1s + THR_;
    float bd = FLT_MAX; int bi = 0x7fffffff;
    for (int t = 0; t < NTILES; ++t) {
      if (tmr[t] <= lim && tid < BN) {
        int c = t * BN + tid;
        const float4* wr4 = reinterpret_cast<const float4*>(w) + (size_t)c * 64;
        float dot = 0.f;
#pragma unroll 8
        for (int k4 = 0; k4 < 64; ++k4) {
          float4 a = znr[k4], b = wr4[k4];
          dot = fmaf(a.x, b.x, dot); dot = fmaf(a.y, b.y, dot);
          dot = fmaf(a.z, b.z, dot); dot = fmaf(a.w, b.w, dot);
        }
        float d = fmaf(-2.0f, dot, wn2[c]);
        if (d < bd || (d == bd && c < bi)) { bd = d; bi = c; }
      }
    }
#pragma unroll
    for (int msk = 1; msk < 64; msk <<= 1) {
      float od = __shfl_xor(bd, msk, 64);
      int   oi = __shfl_xor(bi, msk, 64);
      if (od < bd || (od == bd && oi < bi)) { bd = od; bi = oi; }
    }
    if ((tid & 63) == 0) { wd[tid >> 6] = bd; wi[tid >> 6] = bi; }
    __syncthreads();
    if (tid == 0) {
      float fd = wd[0]; int fi = wi[0];
#pragma unroll
      for (int q = 1; q < 4; ++q)
        if (wd[q] < fd || (wd[q] == fd && wi[q] < fi)) { fd = wd[q]; fi = wi[q]; }
      idxf[row] = fi;
    }
  }
}

// ---------------- kernel 6: gather + loss ----------------
__global__ __launch_bounds__(256) void k_gather(const float* __restrict__ zn,
                                                const float* __restrict__ w,
                                                const int* __restrict__ idxf,
                                                float* __restrict__ zq,
                                                float* __restrict__ idx_out,
                                                float* __restrict__ loss_acc) {
  const int row  = blockIdx.x * 4 + (threadIdx.x >> 6);
  const int lane = threadIdx.x & 63;
  const int bi = idxf[row];
  float4 cv = *(reinterpret_cast<const float4*>(w)  + (size_t)bi  * 64 + lane);
  float4 zv = *(reinterpret_cast<const float4*>(zn) + (size_t)row * 64 + lane);
  *(reinterpret_cast<float4*>(zq) + (size_t)row * 64 + lane) = cv;
  float dx = cv.x - zv.x, dy = cv.y - zv.y, dz = cv.z - zv.z, dw = cv.w - zv.w;
  float s = dx * dx + dy * dy + dz * dz + dw * dw;
#pragma unroll
  for (int o = 32; o > 0; o >>= 1) s += __shfl_xor(s, o, 64);
  if (lane == 0) {
    atomicAdd(loss_acc, s);
    idx_out[row] = (float)bi;
  }
}

__global__ void k_final(const float* __restrict__ loss_acc,
                        float* __restrict__ loss_out) {
  *loss_out = BETA_ * (*loss_acc) * (1.0f / (float)(BT_ * D_));
}

extern "C" void kernel_launch(void* const* d_in, const int* in_sizes, int n_in,
                              void* d_out, int out_size, void* d_ws, size_t ws_size,
                              hipStream_t stream) {
  const float* z = (const float*)d_in[0];
  const float* w = (const float*)d_in[1];

  float* out      = (float*)d_out;
  float* zq       = out;
  float* loss_out = out + (size_t)BT_ * D_;
  float* idx_out  = loss_out + 1;

  char* wsb = (char*)d_ws;
  float*  zn      = (float*)(wsb);                         // 16 MB
  ushort* Acat    = (ushort*)(wsb + 16777216);             // 24 MB
  ushort* Bcat    = (ushort*)(wsb + 41943040);             // 12 MB
  float*  tm      = (float*)(wsb + 54525952);              // 4 MB
  float*  ts      = (float*)(wsb + 58720256);              // 4 MB
  int*    ti      = (int*)(wsb + 62914560);                // 4 MB
  float*  wn2     = (float*)(wsb + 67108864);              // 32 KB
  int*    idxf    = (int*)(wsb + 67141632);                // 64 KB
  int*    flagged = (int*)(wsb + 67207168);                // 64 KB
  int*    count   = (int*)(wsb + 67272704);
  float*  loss_acc = (float*)(wsb + 67272708);

  hipMemsetAsync(count, 0, 8, stream);   // count + loss_acc
  k_prep_z<<<BT_ / 4, 256, 0, stream>>>(z, zn, Acat);
  k_prep_w<<<N_ / 4, 256, 0, stream>>>(w, wn2, Bcat);
  k_coarse<<<(BT_ / BM) * NTILES, 256, 0, stream>>>(Acat, Bcat, wn2, tm, ts, ti);
  k_combine<<<BT_ / 256, 256, 0, stream>>>(tm, ts, ti, idxf, flagged, count);
  k_refine<<<256, 256, 0, stream>>>(zn, w, wn2, tm, flagged, count, idxf);
  k_gather<<<BT_ / 4, 256, 0, stream>>>(zn, w, idxf, zq, idx_out, loss_acc);
  k_final<<<1, 1, 0, stream>>>(loss_acc, loss_out);
}

// Round 3
// 412.472 us; speedup vs baseline: 3.0635x; 1.4136x over previous
//
#include <hip/hip_runtime.h>
#include <float.h>
#include <math.h>

// NormEMAVectorQuantizer via split-bf16 MFMA + exact fp32 refinement.
// z (8,2048,256) f32, weight (8192,256) f32 (unit rows).
// out = [ z_q (16384*256) | loss (1) | indices (16384, as float) ]
//
// Round-3 changes:
//  - k_coarse: 256x128 tile, BK=64, 3-deep LDS pipeline (triple buffer),
//    raw s_barrier + counted s_waitcnt vmcnt(6) (never 0 in steady state),
//    setprio around MFMA clusters, same verified XOR swizzle.
//  - k_refine: 2048 blocks x 128 threads, 4-way FMA accumulators.
//  - k_gather: atomic-free loss partials (reuses ts buffer); k_final reduces.

#define BT_ 16384
#define D_  256
#define N_  8192
#define BETA_ 1.0f
#define THR_ 5e-4f

#define BM 256
#define BN 128
#define NKT 12           // 768 / 64 K-tiles
#define NTILES 64        // N_ / BN

typedef __attribute__((ext_vector_type(8))) short bf16x8;
typedef __attribute__((ext_vector_type(4))) float f32x4;

__device__ __forceinline__ void gld16(void* lds, const void* g) {
  __builtin_amdgcn_global_load_lds(
      (const __attribute__((address_space(1))) void*)g,
      (__attribute__((address_space(3))) void*)lds, 16, 0, 0);
}

__device__ __forceinline__ unsigned short f2bf(float x) {
  unsigned u = __float_as_uint(x);
  u += 0x7FFFu + ((u >> 16) & 1u);
  return (unsigned short)(u >> 16);
}
__device__ __forceinline__ float bf2f(unsigned short h) {
  return __uint_as_float(((unsigned)h) << 16);
}

// ---------------- kernel 1: normalize z, store zn + split A_cat ----------------
__global__ __launch_bounds__(256) void k_prep_z(const float* __restrict__ z,
                                                float* __restrict__ zn,
                                                ushort* __restrict__ Acat) {
  const int row  = blockIdx.x * 4 + (threadIdx.x >> 6);
  const int lane = threadIdx.x & 63;
  float4 v = *(reinterpret_cast<const float4*>(z) + (size_t)row * 64 + lane);
  float s = v.x * v.x + v.y * v.y + v.z * v.z + v.w * v.w;
#pragma unroll
  for (int o = 32; o > 0; o >>= 1) s += __shfl_xor(s, o, 64);
  float dn = fmaxf(sqrtf(s), 1e-12f);
  v.x /= dn; v.y /= dn; v.z /= dn; v.w /= dn;
  *(reinterpret_cast<float4*>(zn) + (size_t)row * 64 + lane) = v;
  ushort4 h  = make_ushort4(f2bf(v.x), f2bf(v.y), f2bf(v.z), f2bf(v.w));
  ushort4 lo = make_ushort4(f2bf(v.x - bf2f(h.x)), f2bf(v.y - bf2f(h.y)),
                            f2bf(v.z - bf2f(h.z)), f2bf(v.w - bf2f(h.w)));
  ushort4* A4 = reinterpret_cast<ushort4*>(Acat);
  size_t rb = (size_t)row * 192 + lane;   // 768/4 = 192 ushort4 per row
  A4[rb]       = h;    // zh
  A4[rb + 64]  = h;    // zh
  A4[rb + 128] = lo;   // zl
}

// ---------------- kernel 2: wn2, split B_cat ----------------
__global__ __launch_bounds__(256) void k_prep_w(const float* __restrict__ w,
                                                float* __restrict__ wn2,
                                                ushort* __restrict__ Bcat) {
  const int row  = blockIdx.x * 4 + (threadIdx.x >> 6);
  const int lane = threadIdx.x & 63;
  float4 v = *(reinterpret_cast<const float4*>(w) + (size_t)row * 64 + lane);
  float s = v.x * v.x + v.y * v.y + v.z * v.z + v.w * v.w;
#pragma unroll
  for (int o = 32; o > 0; o >>= 1) s += __shfl_xor(s, o, 64);
  if (lane == 0) wn2[row] = s;
  ushort4 h  = make_ushort4(f2bf(v.x), f2bf(v.y), f2bf(v.z), f2bf(v.w));
  ushort4 lo = make_ushort4(f2bf(v.x - bf2f(h.x)), f2bf(v.y - bf2f(h.y)),
                            f2bf(v.z - bf2f(h.z)), f2bf(v.w - bf2f(h.w)));
  ushort4* B4 = reinterpret_cast<ushort4*>(Bcat);
  size_t rb = (size_t)row * 192 + lane;
  B4[rb]       = h;    // wh
  B4[rb + 64]  = lo;   // wl
  B4[rb + 128] = h;    // wh
}

// ---------------- kernel 3: pipelined bf16 MFMA GEMM + per-tile (m,s,i) ------
// grid = 64 row-tiles x 64 col-tiles = 4096 blocks, 512 threads (8 waves 4x2).
// LDS: dynamic 3x(A 32KB) + 3x(B 16KB) = 144KB triple buffer.
// Per K-tile: 1 raw barrier, vmcnt(6) counted wait (vmcnt(0) only last tile).
__global__ __launch_bounds__(512, 2) void k_coarse(const ushort* __restrict__ Acat,
                                                   const ushort* __restrict__ Bcat,
                                                   const float* __restrict__ wn2,
                                                   float* __restrict__ tm,
                                                   float* __restrict__ ts,
                                                   int* __restrict__ ti) {
  extern __shared__ char smem[];
  char* ldsA = smem;                 // 3 x 32768
  char* ldsB = smem + 98304;        // 3 x 16384
  __shared__ float wn2s[128];
  __shared__ float red_m[256][2];
  __shared__ float red_s[256][2];
  __shared__ int   red_i[256][2];

  const int tid = threadIdx.x;
  const int l   = tid & 63;
  const int wv  = tid >> 6;
  const int wr  = wv >> 1;       // 0..3 -> rows wr*64
  const int wc  = wv & 1;        // 0..1 -> cols wc*64
  const int bid = blockIdx.x;
  const int swz = (bid & 7) * 512 + (bid >> 3);   // XCD-aware (4096 % 8 == 0)
  const int ct  = swz & 63;
  const int rt  = swz >> 6;
  const int row0 = rt * BM;
  const int col0 = ct * BN;

  if (tid < 128) wn2s[tid] = wn2[col0 + tid];

  // staging source (pre-swizzled): lds (row, cb) <- global (row, cb ^ ((row&7)<<4))
  const int ra = l >> 3;                          // row-in-8
  const int sb = ((l & 7) * 16) ^ (ra << 4);      // source byte col
  const char* aSrc = (const char*)Acat + (size_t)(row0 + wv * 8 + ra) * 1536 + sb;
  const char* bSrc = (const char*)Bcat + (size_t)(col0 + wv * 8 + ra) * 1536 + sb;

  // fragment read offsets (swizzled)
  const int lA   = l & 15;
  const int xsw  = (l & 7) << 4;
  const int kof0 = (((l >> 4) * 16)) ^ xsw;
  const int kof1 = (((l >> 4) * 16) + 64) ^ xsw;

#define STAGE_A(t, h)                                                          \
  do {                                                                         \
    char* _d = ldsA + ((t) % 3) * 32768 + (h) * 16384 + (wv << 10);            \
    const char* _s = aSrc + (size_t)(h) * 128 * 1536 + (size_t)(t) * 128;      \
    gld16(_d, _s);                                                             \
    gld16(_d + 8192, _s + (size_t)64 * 1536);                                  \
  } while (0)
#define STAGE_B(t)                                                             \
  do {                                                                         \
    char* _d = ldsB + ((t) % 3) * 16384 + (wv << 10);                          \
    const char* _s = bSrc + (size_t)(t) * 128;                                 \
    gld16(_d, _s);                                                             \
    gld16(_d + 8192, _s + (size_t)64 * 1536);                                  \
  } while (0)

  f32x4 acc[4][4];
#pragma unroll
  for (int i = 0; i < 4; ++i)
#pragma unroll
    for (int j = 0; j < 4; ++j) acc[i][j] = (f32x4){0.f, 0.f, 0.f, 0.f};

  // prologue: stage tiles 0 and 1 (6 loads each)
  STAGE_A(0, 0); STAGE_A(0, 1); STAGE_B(0);
  STAGE_A(1, 0); STAGE_A(1, 1); STAGE_B(1);

  for (int t = 0; t < NKT; ++t) {
    char* bufA = ldsA + (t % 3) * 32768;
    char* bufB = ldsB + (t % 3) * 16384;
    // boundary: tile t's 6 loads are the oldest; t+1's 6 may stay in flight.
    if (t < NKT - 1) asm volatile("s_waitcnt vmcnt(6) lgkmcnt(0)" ::: "memory");
    else             asm volatile("s_waitcnt vmcnt(0) lgkmcnt(0)" ::: "memory");
    __builtin_amdgcn_s_barrier();
    __builtin_amdgcn_sched_barrier(0);

    bf16x8 a0[4], a1[4], b0, b1;
    // phase 1: ks0, n-frags 0,1
#pragma unroll
    for (int i = 0; i < 4; ++i)
      a0[i] = *(const bf16x8*)(bufA + (wr * 64 + i * 16 + lA) * 128 + kof0);
    b0 = *(const bf16x8*)(bufB + (wc * 64 + 0  + lA) * 128 + kof0);
    b1 = *(const bf16x8*)(bufB + (wc * 64 + 16 + lA) * 128 + kof0);
    if (t < NKT - 2) STAGE_A(t + 2, 0);
    __builtin_amdgcn_s_setprio(1);
#pragma unroll
    for (int i = 0; i < 4; ++i)
      acc[i][0] = __builtin_amdgcn_mfma_f32_16x16x32_bf16(a0[i], b0, acc[i][0], 0, 0, 0);
#pragma unroll
    for (int i = 0; i < 4; ++i)
      acc[i][1] = __builtin_amdgcn_mfma_f32_16x16x32_bf16(a0[i], b1, acc[i][1], 0, 0, 0);
    __builtin_amdgcn_s_setprio(0);
    // phase 2: ks0, n-frags 2,3
    b0 = *(const bf16x8*)(bufB + (wc * 64 + 32 + lA) * 128 + kof0);
    b1 = *(const bf16x8*)(bufB + (wc * 64 + 48 + lA) * 128 + kof0);
    if (t < NKT - 2) STAGE_A(t + 2, 1);
    __builtin_amdgcn_s_setprio(1);
#pragma unroll
    for (int i = 0; i < 4; ++i)
      acc[i][2] = __builtin_amdgcn_mfma_f32_16x16x32_bf16(a0[i], b0, acc[i][2], 0, 0, 0);
#pragma unroll
    for (int i = 0; i < 4; ++i)
      acc[i][3] = __builtin_amdgcn_mfma_f32_16x16x32_bf16(a0[i], b1, acc[i][3], 0, 0, 0);
    __builtin_amdgcn_s_setprio(0);
    // phase 3: ks1, n-frags 0,1
#pragma unroll
    for (int i = 0; i < 4; ++i)
      a1[i] = *(const bf16x8*)(bufA + (wr * 64 + i * 16 + lA) * 128 + kof1);
    b0 = *(const bf16x8*)(bufB + (wc * 64 + 0  + lA) * 128 + kof1);
    b1 = *(const bf16x8*)(bufB + (wc * 64 + 16 + lA) * 128 + kof1);
    if (t < NKT - 2) STAGE_B(t + 2);
    __builtin_amdgcn_s_setprio(1);
#pragma unroll
    for (int i = 0; i < 4; ++i)
      acc[i][0] = __builtin_amdgcn_mfma_f32_16x16x32_bf16(a1[i], b0, acc[i][0], 0, 0, 0);
#pragma unroll
    for (int i = 0; i < 4; ++i)
      acc[i][1] = __builtin_amdgcn_mfma_f32_16x16x32_bf16(a1[i], b1, acc[i][1], 0, 0, 0);
    __builtin_amdgcn_s_setprio(0);
    // phase 4: ks1, n-frags 2,3
    b0 = *(const bf16x8*)(bufB + (wc * 64 + 32 + lA) * 128 + kof1);
    b1 = *(const bf16x8*)(bufB + (wc * 64 + 48 + lA) * 128 + kof1);
    __builtin_amdgcn_s_setprio(1);
#pragma unroll
    for (int i = 0; i < 4; ++i)
      acc[i][2] = __builtin_amdgcn_mfma_f32_16x16x32_bf16(a1[i], b0, acc[i][2], 0, 0, 0);
#pragma unroll
    for (int i = 0; i < 4; ++i)
      acc[i][3] = __builtin_amdgcn_mfma_f32_16x16x32_bf16(a1[i], b1, acc[i][3], 0, 0, 0);
    __builtin_amdgcn_s_setprio(0);
  }
#undef STAGE_A
#undef STAGE_B

  // epilogue: distances + per-row (m, s, idx) over this 128-code tile.
  // C layout (16x16x32): col = lane&15, row = (lane>>4)*4 + reg  [verified r2]
#pragma unroll
  for (int i = 0; i < 4; ++i) {
#pragma unroll
    for (int q = 0; q < 4; ++q) {
      float m = FLT_MAX, s = FLT_MAX; int bi = 0;
#pragma unroll
      for (int j = 0; j < 4; ++j) {
        int cl = wc * 64 + j * 16 + lA;
        float d = fmaf(-2.0f, acc[i][j][q], wn2s[cl]);
        int c = col0 + cl;
        if (d < m) { s = m; m = d; bi = c; }
        else if (d < s) { s = d; }
      }
#pragma unroll
      for (int msk = 1; msk < 16; msk <<= 1) {
        float om = __shfl_xor(m, msk, 64);
        float os = __shfl_xor(s, msk, 64);
        int   oi = __shfl_xor(bi, msk, 64);
        float nsv = fminf(fminf(s, os), fmaxf(m, om));
        if (om < m || (om == m && oi < bi)) { m = om; bi = oi; }
        s = nsv;
      }
      if (lA == 0) {
        int rl = wr * 64 + i * 16 + (l >> 4) * 4 + q;
        red_m[rl][wc] = m; red_s[rl][wc] = s; red_i[rl][wc] = bi;
      }
    }
  }
  __syncthreads();
  if (tid < BM) {
    float m = red_m[tid][0], s = red_s[tid][0]; int bi = red_i[tid][0];
    float om = red_m[tid][1], os = red_s[tid][1]; int oi = red_i[tid][1];
    float nsv = fminf(fminf(s, os), fmaxf(m, om));
    if (om < m || (om == m && oi < bi)) { m = om; bi = oi; }
    s = nsv;
    size_t o = (size_t)ct * BT_ + row0 + tid;
    tm[o] = m; ts[o] = s; ti[o] = bi;
  }
}

// ---------------- kernel 4: combine tiles per row, flag ambiguous ----------------
__global__ __launch_bounds__(256) void k_combine(const float* __restrict__ tm,
                                                 const float* __restrict__ ts,
                                                 const int* __restrict__ ti,
                                                 int* __restrict__ idxf,
                                                 int* __restrict__ flagged,
                                                 int* __restrict__ count) {
  const int row = blockIdx.x * 256 + threadIdx.x;
  float m = FLT_MAX, s = FLT_MAX; int bi = 0x7fffffff;
  for (int t = 0; t < NTILES; ++t) {
    size_t o = (size_t)t * BT_ + row;
    float om = tm[o], os = ts[o]; int oi = ti[o];
    float nsv = fminf(fminf(s, os), fmaxf(m, om));
    if (om < m || (om == m && oi < bi)) { m = om; bi = oi; }
    s = nsv;
  }
  idxf[row] = bi;
  if (s - m <= THR_) {
    int p = atomicAdd(count, 1);
    flagged[p] = row;
  }
}

// ---------------- kernel 5: exact fp32 refinement of flagged rows ----------------
// 2048 blocks x 128 threads; one flagged row per block (grid-stride).
__global__ __launch_bounds__(128) void k_refine(const float* __restrict__ zn,
                                                const float* __restrict__ w,
                                                const float* __restrict__ wn2,
                                                const float* __restrict__ tm,
                                                const int* __restrict__ flagged,
                                                const int* __restrict__ count,
                                                int* __restrict__ idxf) {
  __shared__ float4 znr[64];
  __shared__ float tmr[64];
  __shared__ float m1s;
  __shared__ float wd[2];
  __shared__ int   wi[2];
  const int tid = threadIdx.x;
  const int cnt = *count;
  for (int f = blockIdx.x; f < cnt; f += gridDim.x) {
    __syncthreads();   // protect LDS reuse across iterations
    const int row = flagged[f];
    if (tid < 64) {
      znr[tid] = *(reinterpret_cast<const float4*>(zn) + (size_t)row * 64 + tid);
      float tv = tm[(size_t)tid * BT_ + row];
      tmr[tid] = tv;
      float mm = tv;
#pragma unroll
      for (int msk = 32; msk > 0; msk >>= 1) mm = fminf(mm, __shfl_xor(mm, msk, 64));
      if (tid == 0) m1s = mm;
    }
    __syncthreads();
    const float lim = m1s + THR_;
    float bd = FLT_MAX; int bi = 0x7fffffff;
    for (int t = 0; t < NTILES; ++t) {
      if (tmr[t] <= lim) {
        int c = t * BN + tid;
        const float4* wr4 = reinterpret_cast<const float4*>(w) + (size_t)c * 64;
        float d0 = 0.f, d1 = 0.f, d2 = 0.f, d3 = 0.f;
#pragma unroll
        for (int k4 = 0; k4 < 16; ++k4) {
          float4 a0 = znr[k4 * 4 + 0], b0 = wr4[k4 * 4 + 0];
          float4 a1 = znr[k4 * 4 + 1], b1 = wr4[k4 * 4 + 1];
          float4 a2 = znr[k4 * 4 + 2], b2 = wr4[k4 * 4 + 2];
          float4 a3 = znr[k4 * 4 + 3], b3 = wr4[k4 * 4 + 3];
          d0 = fmaf(a0.x, b0.x, d0); d0 = fmaf(a0.y, b0.y, d0);
          d0 = fmaf(a0.z, b0.z, d0); d0 = fmaf(a0.w, b0.w, d0);
          d1 = fmaf(a1.x, b1.x, d1); d1 = fmaf(a1.y, b1.y, d1);
          d1 = fmaf(a1.z, b1.z, d1); d1 = fmaf(a1.w, b1.w, d1);
          d2 = fmaf(a2.x, b2.x, d2); d2 = fmaf(a2.y, b2.y, d2);
          d2 = fmaf(a2.z, b2.z, d2); d2 = fmaf(a2.w, b2.w, d2);
          d3 = fmaf(a3.x, b3.x, d3); d3 = fmaf(a3.y, b3.y, d3);
          d3 = fmaf(a3.z, b3.z, d3); d3 = fmaf(a3.w, b3.w, d3);
        }
        float dot = (d0 + d1) + (d2 + d3);
        float d = fmaf(-2.0f, dot, wn2[c]);
        if (d < bd || (d == bd && c < bi)) { bd = d; bi = c; }
      }
    }
#pragma unroll
    for (int msk = 1; msk < 64; msk <<= 1) {
      float od = __shfl_xor(bd, msk, 64);
      int   oi = __shfl_xor(bi, msk, 64);
      if (od < bd || (od == bd && oi < bi)) { bd = od; bi = oi; }
    }
    if ((tid & 63) == 0) { wd[tid >> 6] = bd; wi[tid >> 6] = bi; }
    __syncthreads();
    if (tid == 0) {
      float fd = wd[0]; int fi = wi[0];
      if (wd[1] < fd || (wd[1] == fd && wi[1] < fi)) { fd = wd[1]; fi = wi[1]; }
      idxf[row] = fi;
    }
  }
}

// ---------------- kernel 6: gather + loss partials (atomic-free) ----------------
__global__ __launch_bounds__(256) void k_gather(const float* __restrict__ zn,
                                                const float* __restrict__ w,
                                                const int* __restrict__ idxf,
                                                float* __restrict__ zq,
                                                float* __restrict__ idx_out,
                                                float* __restrict__ wpart) {
  const int row  = blockIdx.x * 4 + (threadIdx.x >> 6);
  const int lane = threadIdx.x & 63;
  const int bi = idxf[row];
  float4 cv = *(reinterpret_cast<const float4*>(w)  + (size_t)bi  * 64 + lane);
  float4 zv = *(reinterpret_cast<const float4*>(zn) + (size_t)row * 64 + lane);
  *(reinterpret_cast<float4*>(zq) + (size_t)row * 64 + lane) = cv;
  float dx = cv.x - zv.x, dy = cv.y - zv.y, dz = cv.z - zv.z, dw = cv.w - zv.w;
  float s = dx * dx + dy * dy + dz * dz + dw * dw;
#pragma unroll
  for (int o = 32; o > 0; o >>= 1) s += __shfl_xor(s, o, 64);
  if (lane == 0) {
    wpart[row] = s;
    idx_out[row] = (float)bi;
  }
}

// ---------------- kernel 7: final loss reduction ----------------
__global__ __launch_bounds__(256) void k_final(const float* __restrict__ wpart,
                                               float* __restrict__ loss_out) {
  __shared__ float wsum[4];
  float s = 0.f;
  for (int i = threadIdx.x; i < BT_; i += 256) s += wpart[i];
#pragma unroll
  for (int o = 32; o > 0; o >>= 1) s += __shfl_xor(s, o, 64);
  if ((threadIdx.x & 63) == 0) wsum[threadIdx.x >> 6] = s;
  __syncthreads();
  if (threadIdx.x == 0)
    loss_out[0] = BETA_ * ((wsum[0] + wsum[1]) + (wsum[2] + wsum[3])) *
                  (1.0f / (float)(BT_ * D_));
}

extern "C" void kernel_launch(void* const* d_in, const int* in_sizes, int n_in,
                              void* d_out, int out_size, void* d_ws, size_t ws_size,
                              hipStream_t stream) {
  const float* z = (const float*)d_in[0];
  const float* w = (const float*)d_in[1];

  float* out      = (float*)d_out;
  float* zq       = out;
  float* loss_out = out + (size_t)BT_ * D_;
  float* idx_out  = loss_out + 1;

  char* wsb = (char*)d_ws;
  float*  zn      = (float*)(wsb);                         // 16 MB
  ushort* Acat    = (ushort*)(wsb + 16777216);             // 24 MB
  ushort* Bcat    = (ushort*)(wsb + 41943040);             // 12 MB
  float*  tm      = (float*)(wsb + 54525952);              // 4 MB
  float*  ts      = (float*)(wsb + 58720256);              // 4 MB (reused as wpart)
  int*    ti      = (int*)(wsb + 62914560);                // 4 MB
  float*  wn2     = (float*)(wsb + 67108864);              // 32 KB
  int*    idxf    = (int*)(wsb + 67141632);                // 64 KB
  int*    flagged = (int*)(wsb + 67207168);                // 64 KB
  int*    count   = (int*)(wsb + 67272704);
  float*  wpart   = ts;   // ts is dead after k_combine

  hipFuncSetAttribute((const void*)k_coarse,
                      hipFuncAttributeMaxDynamicSharedMemorySize, 147456);

  hipMemsetAsync(count, 0, 4, stream);
  k_prep_z<<<BT_ / 4, 256, 0, stream>>>(z, zn, Acat);
  k_prep_w<<<N_ / 4, 256, 0, stream>>>(w, wn2, Bcat);
  k_coarse<<<(BT_ / BM) * NTILES, 512, 147456, stream>>>(Acat, Bcat, wn2, tm, ts, ti);
  k_combine<<<BT_ / 256, 256, 0, stream>>>(tm, ts, ti, idxf, flagged, count);
  k_refine<<<2048, 128, 0, stream>>>(zn, w, wn2, tm, flagged, count, idxf);
  k_gather<<<BT_ / 4, 256, 0, stream>>>(zn, w, idxf, zq, idx_out, wpart);
  k_final<<<1, 256, 0, stream>>>(wpart, loss_out);
}